// Round 1
// 872.520 us; speedup vs baseline: 1.0334x; 1.0334x over previous
//
#include <hip/hip_runtime.h>
#include <hip/hip_bf16.h>
#include <stdint.h>

// B=64, C=256, H=W=64, 3x3 SAME conv, per-sample per-tap softmax mask.
// Implicit GEMM per sample: M=256(o), N=4096(y,x), K=2304(tap*256+i), bf16 MFMA.
// This version: (1) mask folded into GEMM via telescoping accumulator rescale
// (removes Wb + wscale_kernel; A-operand is the shared 1.18 MB Wt, L2-resident);
// (2) single-barrier double-buffered K-pipeline (stage next || compute current).

typedef __hip_bfloat16 bf16;
using frag_ab = __attribute__((ext_vector_type(8))) short;  // 8 bf16 (4 VGPRs)
using frag_cd = __attribute__((ext_vector_type(4))) float;  // 4 fp32

#define AS1 __attribute__((address_space(1)))
#define AS3 __attribute__((address_space(3)))

#define NB 64
#define NC 256
#define NH 64
#define NW 64
#define HP 66
#define WP 66
#define KTOT 2304           // 9 * 256
#define XP_ELEMS ((size_t)NB * HP * WP * NC)
#define WT_ELEMS ((size_t)NC * KTOT)                   // 589,824 bf16 = 1.18 MB

__device__ __forceinline__ void gld_lds16(const void* g, void* l) {
    __builtin_amdgcn_global_load_lds((const AS1 void*)g, (AS3 void*)l, 16, 0, 0);
}

// ---- prepass 1: softmax over 9 taps per sample ----
__global__ void softmax_kernel(const float* __restrict__ act, float* __restrict__ mask) {
    int b = threadIdx.x;
    if (b < NB) {
        float v[9], mx = -1e30f;
        #pragma unroll
        for (int i = 0; i < 9; i++) { v[i] = act[b * 9 + i]; mx = fmaxf(mx, v[i]); }
        float s = 0.f;
        #pragma unroll
        for (int i = 0; i < 9; i++) { v[i] = expf(v[i] - mx); s += v[i]; }
        float inv = 1.f / s;
        #pragma unroll
        for (int i = 0; i < 9; i++) mask[b * 9 + i] = v[i] * inv;
    }
}

// ---- prepass 2: transpose w [o][i][tap] f32 -> Wt [o][tap][i] bf16 ----
// coalesced reads (flat o-slice is contiguous); LDS reorder; coalesced uint4 writes
__global__ __launch_bounds__(256) void wt_kernel(const float* __restrict__ w,
                                                 bf16* __restrict__ Wt) {
    int o = blockIdx.x;
    int t = threadIdx.x;
    __shared__ alignas(16) bf16 buf[KTOT];
    #pragma unroll
    for (int j = 0; j < 9; j++) {
        int idx = j * 256 + t;                 // flat within o-slice: i*9+tap
        float v = w[(size_t)o * KTOT + idx];
        int i = idx / 9, tap = idx - i * 9;
        buf[tap * 256 + i] = __float2bfloat16(v);
    }
    __syncthreads();
    const uint4* s = (const uint4*)buf;        // 288 chunks of 16B
    uint4* dst = (uint4*)(Wt + (size_t)o * KTOT);
    dst[t] = s[t];
    if (t < 32) dst[256 + t] = s[256 + t];
}

// ---- prepass 3: zero the pad border of Xp [b][66][66][256] ----
__global__ __launch_bounds__(256) void border_kernel(bf16* __restrict__ Xp) {
    int id = blockIdx.x * 256 + threadIdx.x;
    int ch = id & 31;
    int px = (id >> 5) % 260;
    int b  = (id >> 5) / 260;
    int y, x;
    if (px < 66)       { y = 0;  x = px; }
    else if (px < 132) { y = 65; x = px - 66; }
    else { int e = px - 132; y = 1 + (e >> 1); x = (e & 1) * 65; }
    bf16* dst = Xp + (((size_t)b * HP + y) * WP + x) * NC + ch * 8;
    uint4 z; z.x = 0; z.y = 0; z.z = 0; z.w = 0;
    *(uint4*)dst = z;
}

// ---- prepass 4: NCHW fp32 -> padded NHWC bf16 via LDS transpose (float2 reads) ----
__global__ __launch_bounds__(256) void pad_kernel(const float* __restrict__ inp,
                                                  bf16* __restrict__ Xp) {
    int bid = blockIdx.x;                  // b*256 + y*4 + cb
    int cb = bid & 3;
    int y  = (bid >> 2) & 63;
    int b  = bid >> 8;
    __shared__ bf16 tile[64][66];          // [x][c], pad 66
    int t = threadIdx.x;
    int xp = (t & 31) * 2, tr = t >> 5;    // tr in 0..7
    const float* src = inp + (((size_t)b * NC + cb * 64) * NH + y) * NW + xp;
    #pragma unroll
    for (int ci = 0; ci < 4; ci++) {
        int c = tr * 8 + ci * 2;
        float2 v0 = *(const float2*)(src + (size_t)c * (NH * NW));
        float2 v1 = *(const float2*)(src + (size_t)(c + 1) * (NH * NW));
        union { bf16 h[2]; uint u; } p0, p1;
        p0.h[0] = __float2bfloat16(v0.x); p0.h[1] = __float2bfloat16(v1.x);
        p1.h[0] = __float2bfloat16(v0.y); p1.h[1] = __float2bfloat16(v1.y);
        *(uint*)&tile[xp][c]     = p0.u;
        *(uint*)&tile[xp + 1][c] = p1.u;
    }
    __syncthreads();
    #pragma unroll
    for (int pp = 0; pp < 2; pp++) {
        int x = pp * 32 + (t >> 3);
        int s = t & 7;
        uint u0 = *(const uint*)&tile[x][s * 8 + 0];
        uint u1 = *(const uint*)&tile[x][s * 8 + 2];
        uint u2 = *(const uint*)&tile[x][s * 8 + 4];
        uint u3 = *(const uint*)&tile[x][s * 8 + 6];
        uint4 val; val.x = u0; val.y = u1; val.z = u2; val.w = u3;
        bf16* dst = Xp + (((size_t)b * HP + (y + 1)) * WP + (x + 1)) * NC + cb * 64 + s * 8;
        *(uint4*)dst = val;
    }
}

// ---- main GEMM: k-chunk rotation swizzle + dbuf single-barrier pipeline ----
// Swizzle (unchanged, verified): chunk c of LDS row R holds logical k-chunk
// (c - (R>>1)) & 3. Staging lane l loads logical chunk ((l&3) - ((l>>3)&3)) & 3;
// frag read lane l reads stored chunk ((l>>4) + ((l>>1)&3)) & 3 -> 2-way (free).
// Mask fold: acc_t = (m_{t-1}/m_t) * acc_{t-1} + S_t; out = m_8 * acc_8.
__global__ __launch_bounds__(256) void gemm_kernel(const bf16* __restrict__ Wt,
                                                   const float* __restrict__ mask,
                                                   const bf16* __restrict__ Xp,
                                                   float* __restrict__ out) {
    int bid = blockIdx.x;
    int ntl = bid & 31;         // 32 N-tiles (2 rows x 64 cols each)
    int mt = (bid >> 5) & 1;    // 2 M-tiles of 128 o-channels
    int b  = bid >> 6;          // sample

    __shared__ bf16 As[2][128 * 32];   // [buf][o][k] rows of 64B
    __shared__ bf16 Bs[2][128 * 32];   // [buf][n][k] rows of 64B

    int t = threadIdx.x;
    int w = t >> 6;
    int l = t & 63;

    int so = w * 16 + (l >> 2);                    // staged row 0..63
    int sq = ((l & 3) - ((l >> 3) & 3)) & 3;       // swizzled logical k-chunk
    int sk = sq * 8;                               // element offset

    int ldsw = w * 1024;                           // staging byte offset in buffer

    const bf16* wrow = Wt + (size_t)(mt * 128 + so) * KTOT + sk;
    const bf16* xbase = Xp + (size_t)b * HP * WP * NC;
    int vb = so * NC + sk;

    int wm = w >> 1, wn = w & 1;
    int lm = l & 15;
    int lkq = (((l >> 4) + ((l >> 1) & 3)) & 3) * 8;   // swizzled frag chunk

    frag_cd acc[4][4];
    #pragma unroll
    for (int r = 0; r < 4; r++)
        #pragma unroll
        for (int c = 0; c < 4; c++)
            #pragma unroll
            for (int q = 0; q < 4; q++) acc[r][c][q] = 0.f;

    int apoff = (wm * 64 + lm) * 32 + lkq;
    int bpoff = (wn * 64 + lm) * 32 + lkq;

    // ---- prologue: stage (tap=0, kk=0) into buffer 0 ----
    {
        const bf16* a0 = wrow;                              // tap0 (dy=0,dx=0), kk0
        const bf16* b0 = xbase + ((ntl * 2) * WP) * NC + vb;
        char* dA = (char*)&As[0][0] + ldsw;
        char* dB = (char*)&Bs[0][0] + ldsw;
        gld_lds16(a0,             dA);
        gld_lds16(a0 + 64 * KTOT, dA + 4096);
        gld_lds16(b0,             dB);
        gld_lds16(b0 + WP * NC,   dB + 4096);
    }
    __syncthreads();

    float mprev = 0.f;
    #pragma unroll 1
    for (int tap = 0; tap < 9; tap++) {
        float mcur = mask[b * 9 + tap];
        if (tap) {
            float rsc = mprev / mcur;                       // telescoping rescale
            #pragma unroll
            for (int r = 0; r < 4; r++)
                #pragma unroll
                for (int c = 0; c < 4; c++)
                    #pragma unroll
                    for (int q = 0; q < 4; q++) acc[r][c][q] *= rsc;
        }
        mprev = mcur;

        int dy = tap / 3, dx = tap % 3;
        const bf16* tw = wrow + tap * 256;
        const bf16* tb = xbase + (((ntl * 2 + dy) * WP) + dx) * NC + vb;

        #pragma unroll
        for (int kk = 0; kk < 8; kk++) {
            // stage NEXT K-step into the other buffer (overlaps with compute)
            char* dA = (char*)&As[(kk & 1) ^ 1][0] + ldsw;
            char* dB = (char*)&Bs[(kk & 1) ^ 1][0] + ldsw;
            if (kk < 7) {
                const bf16* a0 = tw + (kk + 1) * 32;
                const bf16* b0 = tb + (kk + 1) * 32;
                gld_lds16(a0,             dA);
                gld_lds16(a0 + 64 * KTOT, dA + 4096);
                gld_lds16(b0,             dB);
                gld_lds16(b0 + WP * NC,   dB + 4096);
            } else if (tap < 8) {
                int tp = tap + 1;
                int ny = tp / 3, nx = tp - 3 * (tp / 3);
                const bf16* a0 = wrow + tp * 256;
                const bf16* b0 = xbase + (((ntl * 2 + ny) * WP) + nx) * NC + vb;
                gld_lds16(a0,             dA);
                gld_lds16(a0 + 64 * KTOT, dA + 4096);
                gld_lds16(b0,             dB);
                gld_lds16(b0 + WP * NC,   dB + 4096);
            }

            // compute current buffer
            const bf16* ap = &As[kk & 1][0] + apoff;
            const bf16* bp = &Bs[kk & 1][0] + bpoff;
            frag_ab af[4], bfr[4];
            #pragma unroll
            for (int r = 0; r < 4; r++) af[r]  = *(const frag_ab*)(ap + r * 16 * 32);
            #pragma unroll
            for (int c = 0; c < 4; c++) bfr[c] = *(const frag_ab*)(bp + c * 16 * 32);
            #pragma unroll
            for (int r = 0; r < 4; r++)
                #pragma unroll
                for (int c = 0; c < 4; c++)
                    acc[r][c] = __builtin_amdgcn_mfma_f32_16x16x32_bf16(
                        af[r], bfr[c], acc[r][c], 0, 0, 0);

            // one barrier per K-step: drains this wave's gld_lds (vmcnt) and
            // ds_reads (lgkm), so next iter may read buf^1 and overwrite buf.
            __syncthreads();
        }
    }

    float m8 = mprev;
    int col = lm;
    int rq = (l >> 4) * 4;
    #pragma unroll
    for (int r = 0; r < 4; r++) {
        #pragma unroll
        for (int c = 0; c < 4; c++) {
            int m = mt * 128 + wm * 64 + r * 16 + rq;
            int n = wn * 64 + c * 16 + col;
            float* po = out + ((size_t)(b * 256 + m)) * (NH * NW) + ntl * 128 + n;
            #pragma unroll
            for (int q = 0; q < 4; q++) po[(size_t)q * (NH * NW)] = m8 * acc[r][c][q];
        }
    }
}

__global__ void diag_kernel(float* out) { out[threadIdx.x] = 12345.0f; }

extern "C" void kernel_launch(void* const* d_in, const int* in_sizes, int n_in,
                              void* d_out, int out_size, void* d_ws, size_t ws_size,
                              hipStream_t stream) {
    const float* inp = (const float*)d_in[0];
    const float* act = (const float*)d_in[1];
    const float* wgt = (const float*)d_in[2];
    float* out = (float*)d_out;

    size_t MASK_OFF = 0;
    size_t WT_OFF = 4096;
    size_t XP_OFF = WT_OFF + WT_ELEMS * sizeof(bf16);   // 4096 + 1,179,648
    size_t NEED  = XP_OFF + XP_ELEMS * sizeof(bf16);    // ~144 MB (was ~218 MB)

    if (ws_size < NEED) {
        diag_kernel<<<1, 256, 0, stream>>>(out);
        return;
    }

    float* mask = (float*)((char*)d_ws + MASK_OFF);
    bf16* Wt = (bf16*)((char*)d_ws + WT_OFF);           // persistent now (A operand)
    bf16* Xp = (bf16*)((char*)d_ws + XP_OFF);

    softmax_kernel<<<1, 64, 0, stream>>>(act, mask);
    wt_kernel<<<NC, 256, 0, stream>>>(wgt, Wt);
    border_kernel<<<(NB * 260 * 32) / 256, 256, 0, stream>>>(Xp);
    pad_kernel<<<NB * NH * 4, 256, 0, stream>>>(inp, Xp);
    gemm_kernel<<<NB * 2 * 32, 256, 0, stream>>>(Wt, mask, Xp, out);
}